// Round 1
// baseline (683.644 us; speedup 1.0000x reference)
//
#include <hip/hip_runtime.h>

#define TQ     128    // query tokens
#define DIM    4096
#define NHEAD  32
#define HDIM   128
#define CPOS   4096   // cache write offset (structural, matches harness)
#define NCHUNK 8      // attention S-chunks: 7x512 cache + 1x(512 cache + 128 new)

typedef __attribute__((ext_vector_type(8))) short short8;   // 8 bf16 in 4 VGPRs
typedef __attribute__((ext_vector_type(4))) float f32x4;

__device__ __forceinline__ unsigned short f2bf(float f) {
    union { float f; unsigned int u; } v; v.f = f;
    unsigned int r = v.u + 0x7FFFu + ((v.u >> 16) & 1u);   // RNE
    return (unsigned short)(r >> 16);
}

// ---------------- kernel 1: x (fp32) -> bf16 ----------------
__global__ __launch_bounds__(256) void cvt_x_kernel(const float* __restrict__ x,
                                                    unsigned short* __restrict__ xbf) {
    int i = blockIdx.x * 256 + threadIdx.x;   // 131072 float4 groups total
    float4 v = ((const float4*)x)[i];
    union { unsigned short u[4]; uint2 w; } o;
    o.u[0] = f2bf(v.x); o.u[1] = f2bf(v.y); o.u[2] = f2bf(v.z); o.u[3] = f2bf(v.w);
    ((uint2*)xbf)[i] = o.w;
}

// ---------------- kernel 2: fused QKV projection ----------------
// C[128 x 12288] = x_bf16 @ [Wq;Wk;Wv]^T + bias, stored bf16.
// Grid 256 WGs, BN=48 (tiles may straddle q/k/v boundary -> per-row/col select).
__global__ __launch_bounds__(256, 2) void qkv_gemm_kernel(
    const unsigned short* __restrict__ xbf,
    const float* __restrict__ wq, const float* __restrict__ wk, const float* __restrict__ wv,
    const float* __restrict__ bq, const float* __restrict__ bk, const float* __restrict__ bv,
    unsigned short* __restrict__ qbf, unsigned short* __restrict__ kbf,
    unsigned short* __restrict__ vbf)
{
    __shared__ unsigned short As[128 * 40];  // 128x32 bf16, stride 40 (pad 8: 2-way free)
    __shared__ unsigned short Bs[48 * 40];
    const int tid = threadIdx.x;
    const int w = tid >> 6, lane = tid & 63;
    const int q = lane >> 4, j = lane & 15;
    const int ncol0 = blockIdx.x * 48;       // column in virtual [12288] N space

    f32x4 acc[2][3];
#pragma unroll
    for (int mi = 0; mi < 2; ++mi)
#pragma unroll
        for (int ni = 0; ni < 3; ++ni) acc[mi][ni] = (f32x4){0.f, 0.f, 0.f, 0.f};

    for (int it = 0; it < 128; ++it) {
        const int k0 = it * 32;
        // stage A: bf16 copy 128x32
#pragma unroll
        for (int g = tid; g < 512; g += 256) {
            int row = g >> 2, col8 = (g & 3) * 8;
            uint4 d = *(const uint4*)(xbf + (size_t)row * DIM + k0 + col8);
            *(uint4*)(As + row * 40 + col8) = d;
        }
        // stage B: fp32 -> bf16, 48x32
#pragma unroll
        for (int f = tid; f < 384; f += 256) {
            int row = f >> 3, col4 = (f & 7) * 4;
            int n = ncol0 + row;
            const float* wp = (n < 4096) ? wq : ((n < 8192) ? wk : wv);
            float4 d = *(const float4*)(wp + (size_t)(n & 4095) * DIM + k0 + col4);
            union { unsigned short u[4]; uint2 v; } o;
            o.u[0] = f2bf(d.x); o.u[1] = f2bf(d.y); o.u[2] = f2bf(d.z); o.u[3] = f2bf(d.w);
            *(uint2*)(Bs + row * 40 + col4) = o.v;
        }
        __syncthreads();
        short8 af[2], bfr[3];
#pragma unroll
        for (int mi = 0; mi < 2; ++mi)
            af[mi] = *(const short8*)(As + (w * 32 + mi * 16 + j) * 40 + q * 8);
#pragma unroll
        for (int ni = 0; ni < 3; ++ni)
            bfr[ni] = *(const short8*)(Bs + (ni * 16 + j) * 40 + q * 8);
#pragma unroll
        for (int mi = 0; mi < 2; ++mi)
#pragma unroll
            for (int ni = 0; ni < 3; ++ni)
                acc[mi][ni] = __builtin_amdgcn_mfma_f32_16x16x32_bf16(af[mi], bfr[ni], acc[mi][ni], 0, 0, 0);
        __syncthreads();
    }
    // epilogue: bias + bf16 store. C layout: col=lane&15, row=(lane>>4)*4+reg.
#pragma unroll
    for (int ni = 0; ni < 3; ++ni) {
        int col = ncol0 + ni * 16 + j;
        int mat = col >> 12, nn = col & 4095;
        const float* bp = (mat == 0) ? bq : ((mat == 1) ? bk : bv);
        unsigned short* op = (mat == 0) ? qbf : ((mat == 1) ? kbf : vbf);
        float bias = bp[nn];
#pragma unroll
        for (int mi = 0; mi < 2; ++mi)
#pragma unroll
            for (int r = 0; r < 4; ++r) {
                int t = w * 32 + mi * 16 + q * 4 + r;
                op[(size_t)t * DIM + nn] = f2bf(acc[mi][ni][r] + bias);
            }
    }
}

// ---------------- kernel 3: flash attention over one (head, S-chunk) ----------------
// Per WG: Q[128x128] vs chunk of K/V, online softmax, partial O + (m,l) to ws.
// S-tiles of 64. RoPE skipped (cancels: same scalar rotation on q and k).
__global__ __launch_bounds__(256, 2) void attn_kernel(
    const unsigned short* __restrict__ qbf, const unsigned short* __restrict__ kbf,
    const unsigned short* __restrict__ vbf,
    const float* __restrict__ kcache, const float* __restrict__ vcache,
    float* __restrict__ opart, float* __restrict__ ml)
{
    __shared__ unsigned short Ks[64 * 136];   // [s][hd] bf16, stride 136
    __shared__ unsigned short Vt[128 * 68];   // [hd][s] bf16 (transposed), stride 68
    __shared__ unsigned short Ps[128 * 72];   // [t][s]  bf16, stride 72
    const int tid = threadIdx.x;
    const int w = tid >> 6, lane = tid & 63;
    const int q = lane >> 4, j = lane & 15;
    const int c = blockIdx.x, h = blockIdx.y;
    const int ntiles = (c == NCHUNK - 1) ? 10 : 8;
    const int s_base = c * 512;
    const float scale = 0.088388347648318447f;  // 1/sqrt(128)

    // preload Q fragments (A-operand: row m=lane&15, k=(lane>>4)*8+e)
    short8 qf[2][4];
#pragma unroll
    for (int mi = 0; mi < 2; ++mi) {
        int t = w * 32 + mi * 16 + j;
#pragma unroll
        for (int ks = 0; ks < 4; ++ks)
            qf[mi][ks] = *(const short8*)(qbf + (size_t)t * DIM + h * HDIM + ks * 32 + q * 8);
    }

    f32x4 oacc[2][8];
    float m_st[2][4], l_st[2][4];
#pragma unroll
    for (int mi = 0; mi < 2; ++mi) {
#pragma unroll
        for (int nh = 0; nh < 8; ++nh) oacc[mi][nh] = (f32x4){0.f, 0.f, 0.f, 0.f};
#pragma unroll
        for (int r = 0; r < 4; ++r) { m_st[mi][r] = -1e30f; l_st[mi][r] = 0.f; }
    }

    for (int tile = 0; tile < ntiles; ++tile) {
        const int s0 = s_base + tile * 64;
        const bool from_new = (s0 >= CPOS);
        // ---- stage K tile (64 x 128) ----
        if (!from_new) {
#pragma unroll
            for (int i = 0; i < 8; ++i) {
                int f = tid + i * 256;
                int row = f >> 5, col4 = (f & 31) * 4;
                float4 d = *(const float4*)(kcache + (size_t)(s0 + row) * DIM + h * HDIM + col4);
                union { unsigned short u[4]; uint2 v; } o;
                o.u[0] = f2bf(d.x); o.u[1] = f2bf(d.y); o.u[2] = f2bf(d.z); o.u[3] = f2bf(d.w);
                *(uint2*)(Ks + row * 136 + col4) = o.v;
            }
        } else {
            int sn = s0 - CPOS;
#pragma unroll
            for (int i = 0; i < 4; ++i) {
                int g = tid + i * 256;
                int row = g >> 4, col8 = (g & 15) * 8;
                uint4 d = *(const uint4*)(kbf + (size_t)(sn + row) * DIM + h * HDIM + col8);
                *(uint4*)(Ks + row * 136 + col8) = d;
            }
        }
        // ---- stage V tile transposed: Vt[hd][s] ----
        if (!from_new) {
#pragma unroll
            for (int i = 0; i < 2; ++i) {
                int ch = tid + i * 256;
                int s4 = ch >> 5, col4 = (ch & 31) * 4;
                const float* src = vcache + (size_t)(s0 + s4 * 4) * DIM + h * HDIM + col4;
                float4 r0 = *(const float4*)(src);
                float4 r1 = *(const float4*)(src + DIM);
                float4 r2 = *(const float4*)(src + 2 * DIM);
                float4 r3 = *(const float4*)(src + 3 * DIM);
#pragma unroll
                for (int i2 = 0; i2 < 4; ++i2) {
                    union { unsigned short u[4]; uint2 v; } o;
                    o.u[0] = f2bf((&r0.x)[i2]); o.u[1] = f2bf((&r1.x)[i2]);
                    o.u[2] = f2bf((&r2.x)[i2]); o.u[3] = f2bf((&r3.x)[i2]);
                    *(uint2*)(Vt + (col4 + i2) * 68 + s4 * 4) = o.v;
                }
            }
        } else {
            int sn = s0 - CPOS;
#pragma unroll
            for (int i = 0; i < 2; ++i) {
                int ch = tid + i * 256;
                int s4 = ch >> 5, col4 = (ch & 31) * 4;
                const unsigned short* src = vbf + (size_t)(sn + s4 * 4) * DIM + h * HDIM + col4;
                union { uint2 v; unsigned short u[4]; } a0, a1, a2, a3;
                a0.v = *(const uint2*)(src);
                a1.v = *(const uint2*)(src + DIM);
                a2.v = *(const uint2*)(src + 2 * DIM);
                a3.v = *(const uint2*)(src + 3 * DIM);
#pragma unroll
                for (int i2 = 0; i2 < 4; ++i2) {
                    union { unsigned short u[4]; uint2 v; } o;
                    o.u[0] = a0.u[i2]; o.u[1] = a1.u[i2]; o.u[2] = a2.u[i2]; o.u[3] = a3.u[i2];
                    *(uint2*)(Vt + (col4 + i2) * 68 + s4 * 4) = o.v;
                }
            }
        }
        __syncthreads();

        // ---- QK^T: wave w owns T rows [w*32, w*32+32), all 64 s cols ----
        f32x4 sacc[2][4];
#pragma unroll
        for (int mi = 0; mi < 2; ++mi)
#pragma unroll
            for (int ni = 0; ni < 4; ++ni) sacc[mi][ni] = (f32x4){0.f, 0.f, 0.f, 0.f};
#pragma unroll
        for (int ks = 0; ks < 4; ++ks) {
            short8 kb[4];
#pragma unroll
            for (int ni = 0; ni < 4; ++ni)
                kb[ni] = *(const short8*)(Ks + (ni * 16 + j) * 136 + ks * 32 + q * 8);
#pragma unroll
            for (int mi = 0; mi < 2; ++mi)
#pragma unroll
                for (int ni = 0; ni < 4; ++ni)
                    sacc[mi][ni] = __builtin_amdgcn_mfma_f32_16x16x32_bf16(qf[mi][ks], kb[ni], sacc[mi][ni], 0, 0, 0);
        }

        // ---- online softmax update ----
#pragma unroll
        for (int mi = 0; mi < 2; ++mi) {
            float alpha[4];
#pragma unroll
            for (int r = 0; r < 4; ++r) {
                float v = sacc[mi][0][r];
#pragma unroll
                for (int ni = 1; ni < 4; ++ni) v = fmaxf(v, sacc[mi][ni][r]);
#pragma unroll
                for (int mask = 1; mask < 16; mask <<= 1)
                    v = fmaxf(v, __shfl_xor(v, mask, 64));
                float mnew = fmaxf(m_st[mi][r], v * scale);
                alpha[r] = __expf(m_st[mi][r] - mnew);
                m_st[mi][r] = mnew;
            }
#pragma unroll
            for (int ni = 0; ni < 4; ++ni)
#pragma unroll
                for (int r = 0; r < 4; ++r)
                    sacc[mi][ni][r] = __expf(sacc[mi][ni][r] * scale - m_st[mi][r]);
#pragma unroll
            for (int r = 0; r < 4; ++r) {
                float s = sacc[mi][0][r] + sacc[mi][1][r] + sacc[mi][2][r] + sacc[mi][3][r];
#pragma unroll
                for (int mask = 1; mask < 16; mask <<= 1)
                    s += __shfl_xor(s, mask, 64);
                l_st[mi][r] = l_st[mi][r] * alpha[r] + s;
            }
            // write P (bf16) to LDS [t][s]; own-wave rows only
#pragma unroll
            for (int ni = 0; ni < 4; ++ni)
#pragma unroll
                for (int r = 0; r < 4; ++r)
                    Ps[(w * 32 + mi * 16 + q * 4 + r) * 72 + ni * 16 + j] = f2bf(sacc[mi][ni][r]);
            // rescale O accumulator (same C-layout rows as scores)
#pragma unroll
            for (int nh = 0; nh < 8; ++nh)
#pragma unroll
                for (int r = 0; r < 4; ++r)
                    oacc[mi][nh][r] *= alpha[r];
        }

        // ---- PV: O[t][hd] += P[t][s] * V[s][hd] ----
#pragma unroll
        for (int ks2 = 0; ks2 < 2; ++ks2) {
            short8 pa[2];
#pragma unroll
            for (int mi = 0; mi < 2; ++mi)
                pa[mi] = *(const short8*)(Ps + (w * 32 + mi * 16 + j) * 72 + ks2 * 32 + q * 8);
#pragma unroll
            for (int nh = 0; nh < 8; ++nh) {
                const unsigned short* p = Vt + (nh * 16 + j) * 68 + ks2 * 32 + q * 8;
                uint2 lo = *(const uint2*)p, hi = *(const uint2*)(p + 4);
                union { unsigned int w4[4]; short8 s; } u;
                u.w4[0] = lo.x; u.w4[1] = lo.y; u.w4[2] = hi.x; u.w4[3] = hi.y;
#pragma unroll
                for (int mi = 0; mi < 2; ++mi)
                    oacc[mi][nh] = __builtin_amdgcn_mfma_f32_16x16x32_bf16(pa[mi], u.s, oacc[mi][nh], 0, 0, 0);
            }
        }
        __syncthreads();
    }

    // ---- write partial O and (m,l) ----
    float* op = opart + ((size_t)(h * NCHUNK + c) * TQ) * HDIM;
#pragma unroll
    for (int mi = 0; mi < 2; ++mi)
#pragma unroll
        for (int nh = 0; nh < 8; ++nh)
#pragma unroll
            for (int r = 0; r < 4; ++r) {
                int t = w * 32 + mi * 16 + q * 4 + r;
                op[(size_t)t * HDIM + nh * 16 + j] = oacc[mi][nh][r];
            }
    if (j == 0) {
        float* mlp = ml + (size_t)(h * NCHUNK + c) * TQ * 2;
#pragma unroll
        for (int mi = 0; mi < 2; ++mi)
#pragma unroll
            for (int r = 0; r < 4; ++r) {
                int t = w * 32 + mi * 16 + q * 4 + r;
                mlp[t * 2] = m_st[mi][r];
                mlp[t * 2 + 1] = l_st[mi][r];
            }
    }
}

// ---------------- kernel 4: flash combine -> bf16 attn_out ----------------
__global__ __launch_bounds__(128) void combine_kernel(const float* __restrict__ opart,
                                                      const float* __restrict__ ml,
                                                      unsigned short* __restrict__ abf) {
    int t = blockIdx.x, h = blockIdx.y, hd = threadIdx.x;
    float mv[NCHUNK], lv[NCHUNK];
    float M = -1e30f;
#pragma unroll
    for (int c = 0; c < NCHUNK; ++c) {
        mv[c] = ml[(size_t)((h * NCHUNK + c) * TQ + t) * 2];
        lv[c] = ml[(size_t)((h * NCHUNK + c) * TQ + t) * 2 + 1];
        M = fmaxf(M, mv[c]);
    }
    float L = 0.f, acc = 0.f;
#pragma unroll
    for (int c = 0; c < NCHUNK; ++c) {
        float wgt = __expf(mv[c] - M);
        L += wgt * lv[c];
        acc += wgt * opart[((size_t)(h * NCHUNK + c) * TQ + t) * HDIM + hd];
    }
    abf[(size_t)t * DIM + h * HDIM + hd] = f2bf(acc / L);
}

// ---------------- kernel 5: output projection (split-K=2, atomic accumulate) ----------------
__global__ __launch_bounds__(256, 2) void out_gemm_kernel(
    const unsigned short* __restrict__ abf, const float* __restrict__ wo,
    const float* __restrict__ bo, float* __restrict__ out)
{
    __shared__ unsigned short As[128 * 40];
    __shared__ unsigned short Bs[32 * 40];
    const int tid = threadIdx.x;
    const int w = tid >> 6, lane = tid & 63;
    const int q = lane >> 4, j = lane & 15;
    const int ncol0 = (blockIdx.x & 127) * 32;
    const int kc = blockIdx.x >> 7;

    f32x4 acc[2][2];
#pragma unroll
    for (int mi = 0; mi < 2; ++mi)
#pragma unroll
        for (int ni = 0; ni < 2; ++ni) acc[mi][ni] = (f32x4){0.f, 0.f, 0.f, 0.f};

    for (int it = 0; it < 64; ++it) {
        const int k0 = kc * 2048 + it * 32;
#pragma unroll
        for (int g = tid; g < 512; g += 256) {
            int row = g >> 2, col8 = (g & 3) * 8;
            uint4 d = *(const uint4*)(abf + (size_t)row * DIM + k0 + col8);
            *(uint4*)(As + row * 40 + col8) = d;
        }
        {
            int row = tid >> 3, col4 = (tid & 7) * 4;
            float4 d = *(const float4*)(wo + (size_t)(ncol0 + row) * DIM + k0 + col4);
            union { unsigned short u[4]; uint2 v; } o;
            o.u[0] = f2bf(d.x); o.u[1] = f2bf(d.y); o.u[2] = f2bf(d.z); o.u[3] = f2bf(d.w);
            *(uint2*)(Bs + row * 40 + col4) = o.v;
        }
        __syncthreads();
        short8 af[2], bfr[2];
#pragma unroll
        for (int mi = 0; mi < 2; ++mi)
            af[mi] = *(const short8*)(As + (w * 32 + mi * 16 + j) * 40 + q * 8);
#pragma unroll
        for (int ni = 0; ni < 2; ++ni)
            bfr[ni] = *(const short8*)(Bs + (ni * 16 + j) * 40 + q * 8);
#pragma unroll
        for (int mi = 0; mi < 2; ++mi)
#pragma unroll
            for (int ni = 0; ni < 2; ++ni)
                acc[mi][ni] = __builtin_amdgcn_mfma_f32_16x16x32_bf16(af[mi], bfr[ni], acc[mi][ni], 0, 0, 0);
        __syncthreads();
    }
#pragma unroll
    for (int ni = 0; ni < 2; ++ni) {
        int col = ncol0 + ni * 16 + j;
        float bias = (kc == 0) ? bo[col] : 0.f;
#pragma unroll
        for (int mi = 0; mi < 2; ++mi)
#pragma unroll
            for (int r = 0; r < 4; ++r) {
                int t = w * 32 + mi * 16 + q * 4 + r;
                atomicAdd(out + (size_t)t * DIM + col, acc[mi][ni][r] + bias);
            }
    }
}

extern "C" void kernel_launch(void* const* d_in, const int* in_sizes, int n_in,
                              void* d_out, int out_size, void* d_ws, size_t ws_size,
                              hipStream_t stream) {
    const float* x      = (const float*)d_in[0];
    const float* wq     = (const float*)d_in[1];
    const float* bq     = (const float*)d_in[2];
    const float* wk     = (const float*)d_in[3];
    const float* bk     = (const float*)d_in[4];
    const float* wv     = (const float*)d_in[5];
    const float* bv     = (const float*)d_in[6];
    const float* wo     = (const float*)d_in[7];
    const float* bo     = (const float*)d_in[8];
    const float* kcache = (const float*)d_in[9];
    const float* vcache = (const float*)d_in[10];
    // d_in[11] = pos (unused: RoPE with a shared scalar pos cancels in q.k),
    // d_in[12] = cache_pos (structural 4096, baked into the grid).
    float* out = (float*)d_out;

    char* ws = (char*)d_ws;
    unsigned short* xbf = (unsigned short*)(ws);                 // 1 MB
    unsigned short* qbf = (unsigned short*)(ws + (1u << 20));    // 1 MB
    unsigned short* kbf = (unsigned short*)(ws + 2u * (1u << 20));
    unsigned short* vbf = (unsigned short*)(ws + 3u * (1u << 20));
    unsigned short* abf = (unsigned short*)(ws + 4u * (1u << 20));
    float* opart = (float*)(ws + 5u * (1u << 20));               // 16 MB
    float* mlbuf = (float*)(ws + 21u * (1u << 20));              // 256 KB

    hipLaunchKernelGGL(cvt_x_kernel, dim3(512), dim3(256), 0, stream, x, xbf);
    hipLaunchKernelGGL(qkv_gemm_kernel, dim3(256), dim3(256), 0, stream,
                       xbf, wq, wk, wv, bq, bk, bv, qbf, kbf, vbf);
    hipLaunchKernelGGL(attn_kernel, dim3(NCHUNK, NHEAD), dim3(256), 0, stream,
                       qbf, kbf, vbf, kcache, vcache, opart, mlbuf);
    hipLaunchKernelGGL(combine_kernel, dim3(TQ, NHEAD), dim3(128), 0, stream,
                       opart, mlbuf, abf);
    hipMemsetAsync(d_out, 0, (size_t)out_size * sizeof(float), stream);
    hipLaunchKernelGGL(out_gemm_kernel, dim3(256), dim3(256), 0, stream, abf, wo, bo, out);
}

// Round 2
// 565.547 us; speedup vs baseline: 1.2088x; 1.2088x over previous
//
#include <hip/hip_runtime.h>

#define TQ     128    // query tokens
#define DIM    4096
#define NHEAD  32
#define HDIM   128
#define CPOS   4096   // cache write offset (structural, matches harness)

typedef __attribute__((ext_vector_type(8))) short short8;   // 8 bf16 in 4 VGPRs
typedef __attribute__((ext_vector_type(4))) float f32x4;

__device__ __forceinline__ unsigned short f2bf(float f) {
    union { float f; unsigned int u; } v; v.f = f;
    unsigned int r = v.u + 0x7FFFu + ((v.u >> 16) & 1u);   // RNE
    return (unsigned short)(r >> 16);
}

// ---------------- kernel 1: x (fp32) -> bf16 ----------------
__global__ __launch_bounds__(256) void cvt_x_kernel(const float* __restrict__ x,
                                                    unsigned short* __restrict__ xbf) {
    int i = blockIdx.x * 256 + threadIdx.x;   // 131072 float4 groups total
    float4 v = ((const float4*)x)[i];
    union { unsigned short u[4]; uint2 w; } o;
    o.u[0] = f2bf(v.x); o.u[1] = f2bf(v.y); o.u[2] = f2bf(v.z); o.u[3] = f2bf(v.w);
    ((uint2*)xbf)[i] = o.w;
}

// ---------------- kernel 2: fused QKV projection, split-K ----------------
// part[kc][128][12288] += x_bf16 @ [Wq;Wk;Wv]^T over K-chunk kc.
// BK=64 with register prefetch of the next tile (loads in flight across barrier).
__global__ __launch_bounds__(256, 4) void qkv_gemm_kernel(
    const unsigned short* __restrict__ xbf,
    const float* __restrict__ wq, const float* __restrict__ wk, const float* __restrict__ wv,
    float* __restrict__ part)
{
    __shared__ unsigned short As[128 * 72];  // 128x64 bf16, stride 72
    __shared__ unsigned short Bs[48 * 72];
    const int tid = threadIdx.x;
    const int w = tid >> 6, lane = tid & 63;
    const int q = lane >> 4, j = lane & 15;
    const int ncol0 = blockIdx.x * 48;       // column in virtual [12288] N space
    const int kc = blockIdx.y, KS = gridDim.y;
    const int kchunk = DIM / KS;
    const int iters = kchunk / 64;
    const int kbase = kc * kchunk;

    f32x4 acc[2][3];
#pragma unroll
    for (int mi = 0; mi < 2; ++mi)
#pragma unroll
        for (int ni = 0; ni < 3; ++ni) acc[mi][ni] = (f32x4){0.f, 0.f, 0.f, 0.f};

    uint4 aReg[4];
    float4 bReg[3];
    // A: 128x64 bf16 -> 1024 x 16B pieces, 4/thread. flat = i*256+tid: row=flat>>3, col8=(flat&7)*8
    // B: 48x64 fp32 -> 768 x float4, 3/thread.   flat = i*256+tid: row=flat>>4, col4=(flat&15)*4
    {
        const int k0 = kbase;
#pragma unroll
        for (int i = 0; i < 4; ++i) {
            int flat = i * 256 + tid;
            aReg[i] = *(const uint4*)(xbf + (size_t)(flat >> 3) * DIM + k0 + (flat & 7) * 8);
        }
#pragma unroll
        for (int i = 0; i < 3; ++i) {
            int flat = i * 256 + tid;
            int n = ncol0 + (flat >> 4);
            const float* wp = (n < 4096) ? wq : ((n < 8192) ? wk : wv);
            bReg[i] = *(const float4*)(wp + (size_t)(n & 4095) * DIM + k0 + (flat & 15) * 4);
        }
    }

    for (int it = 0; it < iters; ++it) {
        if (it > 0) __syncthreads();
#pragma unroll
        for (int i = 0; i < 4; ++i) {
            int flat = i * 256 + tid;
            *(uint4*)(As + (flat >> 3) * 72 + (flat & 7) * 8) = aReg[i];
        }
#pragma unroll
        for (int i = 0; i < 3; ++i) {
            int flat = i * 256 + tid;
            union { unsigned short u[4]; uint2 v; } o;
            o.u[0] = f2bf(bReg[i].x); o.u[1] = f2bf(bReg[i].y);
            o.u[2] = f2bf(bReg[i].z); o.u[3] = f2bf(bReg[i].w);
            *(uint2*)(Bs + (flat >> 4) * 72 + (flat & 15) * 4) = o.v;
        }
        __syncthreads();
        if (it + 1 < iters) {
            const int k0 = kbase + (it + 1) * 64;
#pragma unroll
            for (int i = 0; i < 4; ++i) {
                int flat = i * 256 + tid;
                aReg[i] = *(const uint4*)(xbf + (size_t)(flat >> 3) * DIM + k0 + (flat & 7) * 8);
            }
#pragma unroll
            for (int i = 0; i < 3; ++i) {
                int flat = i * 256 + tid;
                int n = ncol0 + (flat >> 4);
                const float* wp = (n < 4096) ? wq : ((n < 8192) ? wk : wv);
                bReg[i] = *(const float4*)(wp + (size_t)(n & 4095) * DIM + k0 + (flat & 15) * 4);
            }
        }
#pragma unroll
        for (int ks = 0; ks < 2; ++ks) {
            short8 af[2], bfr[3];
#pragma unroll
            for (int mi = 0; mi < 2; ++mi)
                af[mi] = *(const short8*)(As + (w * 32 + mi * 16 + j) * 72 + ks * 32 + q * 8);
#pragma unroll
            for (int ni = 0; ni < 3; ++ni)
                bfr[ni] = *(const short8*)(Bs + (ni * 16 + j) * 72 + ks * 32 + q * 8);
#pragma unroll
            for (int mi = 0; mi < 2; ++mi)
#pragma unroll
                for (int ni = 0; ni < 3; ++ni)
                    acc[mi][ni] = __builtin_amdgcn_mfma_f32_16x16x32_bf16(af[mi], bfr[ni], acc[mi][ni], 0, 0, 0);
        }
    }
    // store fp32 partials. C layout: col=lane&15, row=(lane>>4)*4+reg.
    float* pp = part + (size_t)kc * (TQ * 12288);
#pragma unroll
    for (int ni = 0; ni < 3; ++ni) {
        int col = ncol0 + ni * 16 + j;
#pragma unroll
        for (int mi = 0; mi < 2; ++mi)
#pragma unroll
            for (int r = 0; r < 4; ++r) {
                int t = w * 32 + mi * 16 + q * 4 + r;
                pp[(size_t)t * 12288 + col] = acc[mi][ni][r];
            }
    }
}

// ---------------- kernel 2b: reduce partials + bias -> bf16 q/k/v ----------------
__global__ __launch_bounds__(256) void qkv_reduce_kernel(
    const float* __restrict__ part,
    const float* __restrict__ bq, const float* __restrict__ bk, const float* __restrict__ bv,
    unsigned short* __restrict__ qbf, unsigned short* __restrict__ kbf,
    unsigned short* __restrict__ vbf, int KS)
{
    int idx4 = blockIdx.x * 256 + threadIdx.x;    // over 128*12288/4
    size_t idx = (size_t)idx4 * 4;
    int t = (int)(idx / 12288), n = (int)(idx % 12288);
    float4 s = *(const float4*)(part + idx);
    for (int kc = 1; kc < KS; ++kc) {
        float4 p = *(const float4*)(part + (size_t)kc * (TQ * 12288) + idx);
        s.x += p.x; s.y += p.y; s.z += p.z; s.w += p.w;
    }
    int mat = n >> 12, nn = n & 4095;
    const float* bp = (mat == 0) ? bq : ((mat == 1) ? bk : bv);
    unsigned short* op = (mat == 0) ? qbf : ((mat == 1) ? kbf : vbf);
    float4 b = *(const float4*)(bp + nn);
    union { unsigned short u[4]; uint2 v; } o;
    o.u[0] = f2bf(s.x + b.x); o.u[1] = f2bf(s.y + b.y);
    o.u[2] = f2bf(s.z + b.z); o.u[3] = f2bf(s.w + b.w);
    *(uint2*)(op + (size_t)t * 4096 + nn) = o.v;
}

// ---------------- kernel 3: flash attention over one (head, S-chunk) ----------------
// blockIdx.x in [0, cache_chunks): cache rows [c*c_tiles*64, ...), c_tiles tiles.
// blockIdx.x == cache_chunks: the 128 new tokens (2 tiles) from kbf/vbf.
// RoPE skipped (cancels: same scalar rotation on q and k).
__global__ __launch_bounds__(256, 2) void attn_kernel(
    const unsigned short* __restrict__ qbf, const unsigned short* __restrict__ kbf,
    const unsigned short* __restrict__ vbf,
    const float* __restrict__ kcache, const float* __restrict__ vcache,
    float* __restrict__ opart, float* __restrict__ ml, int c_tiles)
{
    __shared__ unsigned short Ks[64 * 136];   // [s][hd] bf16, stride 136
    __shared__ unsigned short Vt[128 * 68];   // [hd][s] bf16 (transposed), stride 68
    __shared__ unsigned short Ps[128 * 72];   // [t][s]  bf16, stride 72
    const int tid = threadIdx.x;
    const int w = tid >> 6, lane = tid & 63;
    const int q = lane >> 4, j = lane & 15;
    const int c = blockIdx.x, h = blockIdx.y;
    const int nchunk = gridDim.x;
    const bool is_new = (c == nchunk - 1);
    const int ntiles = is_new ? 2 : c_tiles;
    const int s_base = c * c_tiles * 64;      // cache-row base (unused for new chunk)
    const float scale = 0.088388347648318447f;  // 1/sqrt(128)

    // preload Q fragments (A-operand: row m=lane&15, k=(lane>>4)*8+e)
    short8 qf[2][4];
#pragma unroll
    for (int mi = 0; mi < 2; ++mi) {
        int t = w * 32 + mi * 16 + j;
#pragma unroll
        for (int ks = 0; ks < 4; ++ks)
            qf[mi][ks] = *(const short8*)(qbf + (size_t)t * DIM + h * HDIM + ks * 32 + q * 8);
    }

    f32x4 oacc[2][8];
    float m_st[2][4], l_st[2][4];
#pragma unroll
    for (int mi = 0; mi < 2; ++mi) {
#pragma unroll
        for (int nh = 0; nh < 8; ++nh) oacc[mi][nh] = (f32x4){0.f, 0.f, 0.f, 0.f};
#pragma unroll
        for (int r = 0; r < 4; ++r) { m_st[mi][r] = -1e30f; l_st[mi][r] = 0.f; }
    }

    for (int tile = 0; tile < ntiles; ++tile) {
        // ---- stage K tile (64 x 128) ----
        if (!is_new) {
            const int s0 = s_base + tile * 64;
#pragma unroll
            for (int i = 0; i < 8; ++i) {
                int f = tid + i * 256;
                int row = f >> 5, col4 = (f & 31) * 4;
                float4 d = *(const float4*)(kcache + (size_t)(s0 + row) * DIM + h * HDIM + col4);
                union { unsigned short u[4]; uint2 v; } o;
                o.u[0] = f2bf(d.x); o.u[1] = f2bf(d.y); o.u[2] = f2bf(d.z); o.u[3] = f2bf(d.w);
                *(uint2*)(Ks + row * 136 + col4) = o.v;
            }
        } else {
            int sn = tile * 64;
#pragma unroll
            for (int i = 0; i < 4; ++i) {
                int g = tid + i * 256;
                int row = g >> 4, col8 = (g & 15) * 8;
                uint4 d = *(const uint4*)(kbf + (size_t)(sn + row) * DIM + h * HDIM + col8);
                *(uint4*)(Ks + row * 136 + col8) = d;
            }
        }
        // ---- stage V tile transposed: Vt[hd][s] ----
        if (!is_new) {
            const int s0 = s_base + tile * 64;
#pragma unroll
            for (int i = 0; i < 2; ++i) {
                int ch = tid + i * 256;
                int s4 = ch >> 5, col4 = (ch & 31) * 4;
                const float* src = vcache + (size_t)(s0 + s4 * 4) * DIM + h * HDIM + col4;
                float4 r0 = *(const float4*)(src);
                float4 r1 = *(const float4*)(src + DIM);
                float4 r2 = *(const float4*)(src + 2 * DIM);
                float4 r3 = *(const float4*)(src + 3 * DIM);
#pragma unroll
                for (int i2 = 0; i2 < 4; ++i2) {
                    union { unsigned short u[4]; uint2 v; } o;
                    o.u[0] = f2bf((&r0.x)[i2]); o.u[1] = f2bf((&r1.x)[i2]);
                    o.u[2] = f2bf((&r2.x)[i2]); o.u[3] = f2bf((&r3.x)[i2]);
                    *(uint2*)(Vt + (col4 + i2) * 68 + s4 * 4) = o.v;
                }
            }
        } else {
            int sn = tile * 64;
#pragma unroll
            for (int i = 0; i < 2; ++i) {
                int ch = tid + i * 256;
                int s4 = ch >> 5, col4 = (ch & 31) * 4;
                const unsigned short* src = vbf + (size_t)(sn + s4 * 4) * DIM + h * HDIM + col4;
                union { uint2 v; unsigned short u[4]; } a0, a1, a2, a3;
                a0.v = *(const uint2*)(src);
                a1.v = *(const uint2*)(src + DIM);
                a2.v = *(const uint2*)(src + 2 * DIM);
                a3.v = *(const uint2*)(src + 3 * DIM);
#pragma unroll
                for (int i2 = 0; i2 < 4; ++i2) {
                    union { unsigned short u[4]; uint2 v; } o;
                    o.u[0] = a0.u[i2]; o.u[1] = a1.u[i2]; o.u[2] = a2.u[i2]; o.u[3] = a3.u[i2];
                    *(uint2*)(Vt + (col4 + i2) * 68 + s4 * 4) = o.v;
                }
            }
        }
        __syncthreads();

        // ---- QK^T: wave w owns T rows [w*32, w*32+32), all 64 s cols ----
        f32x4 sacc[2][4];
#pragma unroll
        for (int mi = 0; mi < 2; ++mi)
#pragma unroll
            for (int ni = 0; ni < 4; ++ni) sacc[mi][ni] = (f32x4){0.f, 0.f, 0.f, 0.f};
#pragma unroll
        for (int ks = 0; ks < 4; ++ks) {
            short8 kb[4];
#pragma unroll
            for (int ni = 0; ni < 4; ++ni)
                kb[ni] = *(const short8*)(Ks + (ni * 16 + j) * 136 + ks * 32 + q * 8);
#pragma unroll
            for (int mi = 0; mi < 2; ++mi)
#pragma unroll
                for (int ni = 0; ni < 4; ++ni)
                    sacc[mi][ni] = __builtin_amdgcn_mfma_f32_16x16x32_bf16(qf[mi][ks], kb[ni], sacc[mi][ni], 0, 0, 0);
        }

        // ---- online softmax update ----
#pragma unroll
        for (int mi = 0; mi < 2; ++mi) {
            float alpha[4];
#pragma unroll
            for (int r = 0; r < 4; ++r) {
                float v = sacc[mi][0][r];
#pragma unroll
                for (int ni = 1; ni < 4; ++ni) v = fmaxf(v, sacc[mi][ni][r]);
#pragma unroll
                for (int mask = 1; mask < 16; mask <<= 1)
                    v = fmaxf(v, __shfl_xor(v, mask, 64));
                float mnew = fmaxf(m_st[mi][r], v * scale);
                alpha[r] = __expf(m_st[mi][r] - mnew);
                m_st[mi][r] = mnew;
            }
#pragma unroll
            for (int ni = 0; ni < 4; ++ni)
#pragma unroll
                for (int r = 0; r < 4; ++r)
                    sacc[mi][ni][r] = __expf(sacc[mi][ni][r] * scale - m_st[mi][r]);
#pragma unroll
            for (int r = 0; r < 4; ++r) {
                float s = sacc[mi][0][r] + sacc[mi][1][r] + sacc[mi][2][r] + sacc[mi][3][r];
#pragma unroll
                for (int mask = 1; mask < 16; mask <<= 1)
                    s += __shfl_xor(s, mask, 64);
                l_st[mi][r] = l_st[mi][r] * alpha[r] + s;
            }
            // write P (bf16) to LDS [t][s]; own-wave rows only
#pragma unroll
            for (int ni = 0; ni < 4; ++ni)
#pragma unroll
                for (int r = 0; r < 4; ++r)
                    Ps[(w * 32 + mi * 16 + q * 4 + r) * 72 + ni * 16 + j] = f2bf(sacc[mi][ni][r]);
            // rescale O accumulator (same C-layout rows as scores)
#pragma unroll
            for (int nh = 0; nh < 8; ++nh)
#pragma unroll
                for (int r = 0; r < 4; ++r)
                    oacc[mi][nh][r] *= alpha[r];
        }

        // ---- PV: O[t][hd] += P[t][s] * V[s][hd] ----
#pragma unroll
        for (int ks2 = 0; ks2 < 2; ++ks2) {
            short8 pa[2];
#pragma unroll
            for (int mi = 0; mi < 2; ++mi)
                pa[mi] = *(const short8*)(Ps + (w * 32 + mi * 16 + j) * 72 + ks2 * 32 + q * 8);
#pragma unroll
            for (int nh = 0; nh < 8; ++nh) {
                const unsigned short* p = Vt + (nh * 16 + j) * 68 + ks2 * 32 + q * 8;
                uint2 lo = *(const uint2*)p, hi = *(const uint2*)(p + 4);
                union { unsigned int w4[4]; short8 s; } u;
                u.w4[0] = lo.x; u.w4[1] = lo.y; u.w4[2] = hi.x; u.w4[3] = hi.y;
#pragma unroll
                for (int mi = 0; mi < 2; ++mi)
                    oacc[mi][nh] = __builtin_amdgcn_mfma_f32_16x16x32_bf16(pa[mi], u.s, oacc[mi][nh], 0, 0, 0);
            }
        }
        __syncthreads();
    }

    // ---- write partial O and (m,l) ----
    float* op = opart + ((size_t)(h * nchunk + c) * TQ) * HDIM;
#pragma unroll
    for (int mi = 0; mi < 2; ++mi)
#pragma unroll
        for (int nh = 0; nh < 8; ++nh)
#pragma unroll
            for (int r = 0; r < 4; ++r) {
                int t = w * 32 + mi * 16 + q * 4 + r;
                op[(size_t)t * HDIM + nh * 16 + j] = oacc[mi][nh][r];
            }
    if (j == 0) {
        float* mlp = ml + (size_t)(h * nchunk + c) * TQ * 2;
#pragma unroll
        for (int mi = 0; mi < 2; ++mi)
#pragma unroll
            for (int r = 0; r < 4; ++r) {
                int t = w * 32 + mi * 16 + q * 4 + r;
                mlp[t * 2] = m_st[mi][r];
                mlp[t * 2 + 1] = l_st[mi][r];
            }
    }
}

// ---------------- kernel 4: flash combine -> bf16 attn_out ----------------
__global__ __launch_bounds__(128) void combine_kernel(const float* __restrict__ opart,
                                                      const float* __restrict__ ml,
                                                      unsigned short* __restrict__ abf,
                                                      int nchunk) {
    int t = blockIdx.x, h = blockIdx.y, hd = threadIdx.x;
    float M = -1e30f;
    for (int c = 0; c < nchunk; ++c)
        M = fmaxf(M, ml[(size_t)((h * nchunk + c) * TQ + t) * 2]);
    float L = 0.f, acc = 0.f;
    for (int c = 0; c < nchunk; ++c) {
        float m = ml[(size_t)((h * nchunk + c) * TQ + t) * 2];
        float l = ml[(size_t)((h * nchunk + c) * TQ + t) * 2 + 1];
        float wgt = __expf(m - M);
        L += wgt * l;
        acc += wgt * opart[((size_t)(h * nchunk + c) * TQ + t) * HDIM + hd];
    }
    abf[(size_t)t * DIM + h * HDIM + hd] = f2bf(acc / L);
}

// ---------------- kernel 5: output projection, split-K, partials ----------------
__global__ __launch_bounds__(256, 4) void out_gemm_kernel(
    const unsigned short* __restrict__ abf, const float* __restrict__ wo,
    float* __restrict__ part)
{
    __shared__ unsigned short As[128 * 72];
    __shared__ unsigned short Bs[32 * 72];
    const int tid = threadIdx.x;
    const int w = tid >> 6, lane = tid & 63;
    const int q = lane >> 4, j = lane & 15;
    const int ncol0 = blockIdx.x * 32;
    const int kc = blockIdx.y, KO = gridDim.y;
    const int kchunk = DIM / KO;
    const int iters = kchunk / 64;
    const int kbase = kc * kchunk;

    f32x4 acc[2][2];
#pragma unroll
    for (int mi = 0; mi < 2; ++mi)
#pragma unroll
        for (int ni = 0; ni < 2; ++ni) acc[mi][ni] = (f32x4){0.f, 0.f, 0.f, 0.f};

    uint4 aReg[4];
    float4 bReg[2];
    {
        const int k0 = kbase;
#pragma unroll
        for (int i = 0; i < 4; ++i) {
            int flat = i * 256 + tid;
            aReg[i] = *(const uint4*)(abf + (size_t)(flat >> 3) * DIM + k0 + (flat & 7) * 8);
        }
#pragma unroll
        for (int i = 0; i < 2; ++i) {
            int flat = i * 256 + tid;
            bReg[i] = *(const float4*)(wo + (size_t)(ncol0 + (flat >> 4)) * DIM + k0 + (flat & 15) * 4);
        }
    }

    for (int it = 0; it < iters; ++it) {
        if (it > 0) __syncthreads();
#pragma unroll
        for (int i = 0; i < 4; ++i) {
            int flat = i * 256 + tid;
            *(uint4*)(As + (flat >> 3) * 72 + (flat & 7) * 8) = aReg[i];
        }
#pragma unroll
        for (int i = 0; i < 2; ++i) {
            int flat = i * 256 + tid;
            union { unsigned short u[4]; uint2 v; } o;
            o.u[0] = f2bf(bReg[i].x); o.u[1] = f2bf(bReg[i].y);
            o.u[2] = f2bf(bReg[i].z); o.u[3] = f2bf(bReg[i].w);
            *(uint2*)(Bs + (flat >> 4) * 72 + (flat & 15) * 4) = o.v;
        }
        __syncthreads();
        if (it + 1 < iters) {
            const int k0 = kbase + (it + 1) * 64;
#pragma unroll
            for (int i = 0; i < 4; ++i) {
                int flat = i * 256 + tid;
                aReg[i] = *(const uint4*)(abf + (size_t)(flat >> 3) * DIM + k0 + (flat & 7) * 8);
            }
#pragma unroll
            for (int i = 0; i < 2; ++i) {
                int flat = i * 256 + tid;
                bReg[i] = *(const float4*)(wo + (size_t)(ncol0 + (flat >> 4)) * DIM + k0 + (flat & 15) * 4);
            }
        }
#pragma unroll
        for (int ks = 0; ks < 2; ++ks) {
            short8 af[2], bfr[2];
#pragma unroll
            for (int mi = 0; mi < 2; ++mi)
                af[mi] = *(const short8*)(As + (w * 32 + mi * 16 + j) * 72 + ks * 32 + q * 8);
#pragma unroll
            for (int ni = 0; ni < 2; ++ni)
                bfr[ni] = *(const short8*)(Bs + (ni * 16 + j) * 72 + ks * 32 + q * 8);
#pragma unroll
            for (int mi = 0; mi < 2; ++mi)
#pragma unroll
                for (int ni = 0; ni < 2; ++ni)
                    acc[mi][ni] = __builtin_amdgcn_mfma_f32_16x16x32_bf16(af[mi], bfr[ni], acc[mi][ni], 0, 0, 0);
        }
    }
    float* pp = part + (size_t)kc * (TQ * DIM);
#pragma unroll
    for (int ni = 0; ni < 2; ++ni) {
        int col = ncol0 + ni * 16 + j;
#pragma unroll
        for (int mi = 0; mi < 2; ++mi)
#pragma unroll
            for (int r = 0; r < 4; ++r) {
                int t = w * 32 + mi * 16 + q * 4 + r;
                pp[(size_t)t * DIM + col] = acc[mi][ni][r];
            }
    }
}

// ---------------- kernel 5b: reduce out partials + bias -> fp32 out ----------------
__global__ __launch_bounds__(256) void out_reduce_kernel(
    const float* __restrict__ part, const float* __restrict__ bo,
    float* __restrict__ out, int KO)
{
    int idx4 = blockIdx.x * 256 + threadIdx.x;    // over 128*4096/4
    size_t idx = (size_t)idx4 * 4;
    int col = (int)(idx % DIM);
    float4 s = *(const float4*)(part + idx);
    for (int kc = 1; kc < KO; ++kc) {
        float4 p = *(const float4*)(part + (size_t)kc * (TQ * DIM) + idx);
        s.x += p.x; s.y += p.y; s.z += p.z; s.w += p.w;
    }
    float4 b = *(const float4*)(bo + col);
    s.x += b.x; s.y += b.y; s.z += b.z; s.w += b.w;
    *(float4*)(out + idx) = s;
}

extern "C" void kernel_launch(void* const* d_in, const int* in_sizes, int n_in,
                              void* d_out, int out_size, void* d_ws, size_t ws_size,
                              hipStream_t stream) {
    const float* x      = (const float*)d_in[0];
    const float* wq     = (const float*)d_in[1];
    const float* bq     = (const float*)d_in[2];
    const float* wk     = (const float*)d_in[3];
    const float* bk     = (const float*)d_in[4];
    const float* wv     = (const float*)d_in[5];
    const float* bv     = (const float*)d_in[6];
    const float* wo     = (const float*)d_in[7];
    const float* bo     = (const float*)d_in[8];
    const float* kcache = (const float*)d_in[9];
    const float* vcache = (const float*)d_in[10];
    // d_in[11] = pos (unused: RoPE with a shared scalar pos cancels in q.k),
    // d_in[12] = cache_pos (structural 4096, baked into the grid).
    float* out = (float*)d_out;

    const size_t MB = 1u << 20;
    char* ws = (char*)d_ws;
    unsigned short* xbf = (unsigned short*)(ws);              // 1 MB
    unsigned short* qbf = (unsigned short*)(ws + 1 * MB);     // 1 MB each
    unsigned short* kbf = (unsigned short*)(ws + 2 * MB);
    unsigned short* vbf = (unsigned short*)(ws + 3 * MB);
    unsigned short* abf = (unsigned short*)(ws + 4 * MB);
    char* pool = ws + 5 * MB;   // sequentially-dead large buffers alias here

    // config: big if ws allows (pool needs max(KS*6.29MB, (CCH+1)*2.1MB + ml, KO*2.1MB))
    int KS, CCH, KO;
    if (ws_size >= 43 * MB) { KS = 4; CCH = 16; KO = 8; }
    else                    { KS = 2; CCH = 8;  KO = 4; }
    const int c_tiles = (CPOS / CCH) / 64;     // tiles of 64 per cache chunk
    const int nchunk = CCH + 1;

    float* part_qkv = (float*)pool;                               // KS * 6.29 MB
    float* opart    = (float*)pool;                               // nchunk * 2.1 MB
    float* mlbuf    = (float*)(pool + (size_t)nchunk * NHEAD * TQ * HDIM * 4);
    float* part_out = (float*)pool;                               // KO * 2.1 MB

    hipLaunchKernelGGL(cvt_x_kernel, dim3(512), dim3(256), 0, stream, x, xbf);
    hipLaunchKernelGGL(qkv_gemm_kernel, dim3(256, KS), dim3(256), 0, stream,
                       xbf, wq, wk, wv, part_qkv);
    hipLaunchKernelGGL(qkv_reduce_kernel, dim3(1536), dim3(256), 0, stream,
                       part_qkv, bq, bk, bv, qbf, kbf, vbf, KS);
    hipLaunchKernelGGL(attn_kernel, dim3(nchunk, NHEAD), dim3(256), 0, stream,
                       qbf, kbf, vbf, kcache, vcache, opart, mlbuf, c_tiles);
    hipLaunchKernelGGL(combine_kernel, dim3(TQ, NHEAD), dim3(128), 0, stream,
                       opart, mlbuf, abf, nchunk);
    hipLaunchKernelGGL(out_gemm_kernel, dim3(128, KO), dim3(256), 0, stream,
                       abf, wo, part_out);
    hipLaunchKernelGGL(out_reduce_kernel, dim3(512), dim3(256), 0, stream,
                       part_out, bo, out, KO);
}